// Round 1
// baseline (11717.437 us; speedup 1.0000x reference)
//
#include <hip/hip_runtime.h>
#include <stdint.h>

#define T_TOK 8192
#define DIM   2048
#define NEXP  16
#define NLAY  4
#define TOPK  8

#define BM 128
#define BN 128
#define BK 64

typedef _Float16 f16;
typedef f16   f16x8 __attribute__((ext_vector_type(8)));
typedef f16   f16x4 __attribute__((ext_vector_type(4)));
typedef float f32x4 __attribute__((ext_vector_type(4)));
typedef float fv4   __attribute__((ext_vector_type(4)));
typedef uint32_t u32x4 __attribute__((ext_vector_type(4)));

// ---------------- routing: fp32 logits, softmax, exact top-8 ----------------
// one wave per token; lanes 0..15 own one expert each for the append step
__global__ __launch_bounds__(256) void route_kernel(
    const float* __restrict__ h, const float* __restrict__ gw,
    int* __restrict__ cnt, int* __restrict__ tok, float* __restrict__ wt)
{
  int gid  = blockIdx.x * 256 + threadIdx.x;
  int t    = gid >> 6;
  int lane = threadIdx.x & 63;
  if (t >= T_TOK) return;
  const float* hr = h + (size_t)t * DIM;
  float hreg[32];
#pragma unroll
  for (int j = 0; j < 32; ++j) hreg[j] = hr[lane + 64 * j];
  float p[16];
#pragma unroll
  for (int e = 0; e < 16; ++e) {
    const float* gr = gw + e * DIM;
    float s = 0.f;
#pragma unroll
    for (int j = 0; j < 32; ++j) s += hreg[j] * gr[lane + 64 * j];
#pragma unroll
    for (int off = 32; off; off >>= 1) s += __shfl_xor(s, off);
    p[e] = s;
  }
  float mx = p[0];
#pragma unroll
  for (int e = 1; e < 16; ++e) mx = fmaxf(mx, p[e]);
  float sum = 0.f;
#pragma unroll
  for (int e = 0; e < 16; ++e) { p[e] = expf(p[e] - mx); sum += p[e]; }
  float inv = 1.f / sum;
#pragma unroll
  for (int e = 0; e < 16; ++e) p[e] *= inv;
  if (lane < 16) {
    float mine = p[lane];
    int rank = 0;
#pragma unroll
    for (int j = 0; j < 16; ++j)
      rank += (p[j] > mine) || (p[j] == mine && j < lane);  // jax top_k tie-break
    if (rank < TOPK) {
      int pos = atomicAdd(&cnt[lane], 1);
      tok[lane * T_TOK + pos] = t;
      wt [lane * T_TOK + pos] = mine;
    }
  }
}

// ------------- fp32 -> scaled fp16 hi/lo split (x*64 = hi + lo) -------------
__global__ __launch_bounds__(256) void split_kernel(
    const float* __restrict__ src, f16* __restrict__ hi, f16* __restrict__ lo, int n4)
{
  int i0 = blockIdx.x * 256 + threadIdx.x;
  int stride = gridDim.x * 256;
  for (int i = i0; i < n4; i += stride) {
    fv4 v = ((const fv4*)src)[i];
    f16x4 h4, l4;
#pragma unroll
    for (int j = 0; j < 4; ++j) {
      float x = v[j] * 64.f;       // pre-scale keeps lo parts out of fp16 denormal range
      f16 hh = (f16)x;
      h4[j] = hh;
      l4[j] = (f16)(x - (float)hh);
    }
    ((f16x4*)hi)[i] = h4;
    ((f16x4*)lo)[i] = l4;
  }
}

// ------------------- gathered grouped GEMM, 3-term fp16x2 -------------------
// grid: (DIM/BN, T_TOK/BM worst case, NEXP); 256 thr = 4 waves (2m x 2n), wave tile 64x64
__global__ __launch_bounds__(256, 2) void moe_gemm(
    const f16* __restrict__ A1, const f16* __restrict__ A2,
    const f16* __restrict__ W1, const f16* __restrict__ W2,
    const int* __restrict__ tok, const float* __restrict__ wt,
    const int* __restrict__ cnt, float* __restrict__ out)
{
  const int e  = blockIdx.z;
  const int ce = cnt[e];
  const int m0 = blockIdx.y * BM;
  if (m0 >= ce) return;
  const int n0 = blockIdx.x * BN;

  __shared__ f16 lsA1[BM * BK];
  __shared__ f16 lsA2[BM * BK];
  __shared__ f16 lsB1[BN * BK];
  __shared__ f16 lsB2[BN * BK];

  const int tid  = threadIdx.x;
  const int srow = tid & 127;     // staging row (one row per thread, 2 thr/row via cc)
  const int cc   = tid >> 7;      // chunk-group: chunks cc*4+q  (8 x 16B chunks per row)
  const int lpos = min(m0 + srow, ce - 1);
  const int gtok = tok[e * T_TOK + lpos];
  const f16* gA1 = A1 + (size_t)gtok * DIM;
  const f16* gA2 = A2 + (size_t)gtok * DIM;
  const f16* gB1 = W1 + ((size_t)e * DIM + n0 + srow) * DIM;
  const f16* gB2 = W2 + ((size_t)e * DIM + n0 + srow) * DIM;

  int woff[4];                    // swizzled LDS offsets (f16 units): chunk c -> c ^ (row&7)
#pragma unroll
  for (int q = 0; q < 4; ++q) {
    int c = cc * 4 + q;
    woff[q] = srow * BK + ((c ^ (srow & 7)) * 8);
  }

  u32x4 pf[4][4];
  auto stage_load = [&](int k0) {
#pragma unroll
    for (int q = 0; q < 4; ++q) {
      int koff = k0 + (cc * 4 + q) * 8;
      pf[0][q] = *(const u32x4*)(gA1 + koff);
      pf[1][q] = *(const u32x4*)(gA2 + koff);
      pf[2][q] = *(const u32x4*)(gB1 + koff);
      pf[3][q] = *(const u32x4*)(gB2 + koff);
    }
  };
  auto stage_write = [&]() {
#pragma unroll
    for (int q = 0; q < 4; ++q) {
      *(u32x4*)&lsA1[woff[q]] = pf[0][q];
      *(u32x4*)&lsA2[woff[q]] = pf[1][q];
      *(u32x4*)&lsB1[woff[q]] = pf[2][q];
      *(u32x4*)&lsB2[woff[q]] = pf[3][q];
    }
  };

  const int lane = tid & 63;
  const int wm = (tid >> 6) & 1;
  const int wn = (tid >> 7);
  const int lr = lane & 15;
  const int lk = lane >> 4;

  f32x4 acc[4][4];
#pragma unroll
  for (int i = 0; i < 4; ++i)
#pragma unroll
    for (int j = 0; j < 4; ++j)
      acc[i][j] = (f32x4){0.f, 0.f, 0.f, 0.f};

  stage_load(0);
  stage_write();
  __syncthreads();

  for (int kt = 0; kt < DIM / BK; ++kt) {
    if (kt + 1 < DIM / BK) stage_load((kt + 1) * BK);   // loads fly under compute
#pragma unroll
    for (int ks = 0; ks < 2; ++ks) {
      f16x8 a1f[4], a2f[4], b1f[4], b2f[4];
#pragma unroll
      for (int mi = 0; mi < 4; ++mi) {
        int r = wm * 64 + mi * 16 + lr;
        int c = ks * 4 + lk;
        int off = r * BK + ((c ^ (r & 7)) * 8);
        a1f[mi] = *(const f16x8*)&lsA1[off];
        a2f[mi] = *(const f16x8*)&lsA2[off];
      }
#pragma unroll
      for (int ni = 0; ni < 4; ++ni) {
        int r = wn * 64 + ni * 16 + lr;
        int c = ks * 4 + lk;
        int off = r * BK + ((c ^ (r & 7)) * 8);
        b1f[ni] = *(const f16x8*)&lsB1[off];
        b2f[ni] = *(const f16x8*)&lsB2[off];
      }
#pragma unroll
      for (int mi = 0; mi < 4; ++mi)
#pragma unroll
        for (int ni = 0; ni < 4; ++ni) {
          acc[mi][ni] = __builtin_amdgcn_mfma_f32_16x16x32_f16(a1f[mi], b1f[ni], acc[mi][ni], 0, 0, 0);
          acc[mi][ni] = __builtin_amdgcn_mfma_f32_16x16x32_f16(a1f[mi], b2f[ni], acc[mi][ni], 0, 0, 0);
          acc[mi][ni] = __builtin_amdgcn_mfma_f32_16x16x32_f16(a2f[mi], b1f[ni], acc[mi][ni], 0, 0, 0);
        }
    }
    __syncthreads();
    if (kt + 1 < DIM / BK) {
      stage_write();
      __syncthreads();
    }
  }

  // epilogue: out[tok, n] += w * acc / 4096  (descale 64*64)
  const int ebase = e * T_TOK;
#pragma unroll
  for (int mi = 0; mi < 4; ++mi) {
#pragma unroll
    for (int q = 0; q < 4; ++q) {
      int pos = m0 + wm * 64 + mi * 16 + lk * 4 + q;
      if (pos < ce) {
        int tt = tok[ebase + pos];
        float sc = wt[ebase + pos] * (1.0f / 4096.0f);
        float* orow = out + (size_t)tt * DIM + n0 + wn * 64;
#pragma unroll
        for (int ni = 0; ni < 4; ++ni)
          atomicAdd(&orow[ni * 16 + lr], sc * acc[mi][ni][q]);
      }
    }
  }
}

// ------------------------------- launcher -----------------------------------
extern "C" void kernel_launch(void* const* d_in, const int* in_sizes, int n_in,
                              void* d_out, int out_size, void* d_ws, size_t ws_size,
                              hipStream_t stream) {
  const float* x  = (const float*)d_in[0];
  const float* gw = (const float*)d_in[1];
  const float* ew = (const float*)d_in[2];
  float* out = (float*)d_out;

  char* ws = (char*)d_ws;
  float* hA  = (float*)ws;                        // 64 MB fp32 h ping buffer
  f16*   A1  = (f16*)(ws + 67108864ull);          // 32 MB
  f16*   A2  = (f16*)(ws + 100663296ull);         // 32 MB
  f16*   W1  = (f16*)(ws + 134217728ull);         // 128 MB (current layer)
  f16*   W2  = (f16*)(ws + 268435456ull);         // 128 MB
  int*   tok = (int*)(ws + 402653184ull);         // 512 KB
  float* wt  = (float*)(ws + 403177472ull);       // 512 KB
  int*   cnt = (int*)(ws + 403701760ull);         // 64 B

  const float* hin = x;
  float* houts[4] = {hA, out, hA, out};           // ping-pong; final layer -> d_out
  for (int l = 0; l < NLAY; ++l) {
    float* hout = houts[l];
    hipMemsetAsync(cnt, 0, 64, stream);
    route_kernel<<<T_TOK / 4, 256, 0, stream>>>(hin, gw + (size_t)l * NEXP * DIM, cnt, tok, wt);
    split_kernel<<<4096, 256, 0, stream>>>(hin, A1, A2, T_TOK * DIM / 4);
    split_kernel<<<8192, 256, 0, stream>>>(ew + (size_t)l * NEXP * DIM * DIM, W1, W2, NEXP * DIM * DIM / 4);
    hipMemsetAsync(hout, 0, (size_t)T_TOK * DIM * 4, stream);
    dim3 g(DIM / BN, T_TOK / BM, NEXP);
    moe_gemm<<<g, 256, 0, stream>>>(A1, A2, W1, W2, tok, wt, cnt, hout);
    hin = hout;
  }
}

// Round 2
// 7910.611 us; speedup vs baseline: 1.4812x; 1.4812x over previous
//
#include <hip/hip_runtime.h>
#include <stdint.h>

#define T_TOK 8192
#define DIM   2048
#define NEXP  16
#define NLAY  4
#define TOPK  8

#define BM 256
#define BN 256
#define BK 64
#define NT 96   // 3 term-phases x 32 K-tiles

typedef _Float16 f16;
typedef f16   f16x8 __attribute__((ext_vector_type(8)));
typedef f16   f16x4 __attribute__((ext_vector_type(4)));
typedef float f32x4 __attribute__((ext_vector_type(4)));
typedef float fv4   __attribute__((ext_vector_type(4)));

// ---------------- routing: fp32 logits, softmax, exact top-8 ----------------
__global__ __launch_bounds__(256) void route_kernel(
    const float* __restrict__ h, const float* __restrict__ gw,
    int* __restrict__ cnt, int* __restrict__ tok, float* __restrict__ wt)
{
  int gid  = blockIdx.x * 256 + threadIdx.x;
  int t    = gid >> 6;
  int lane = threadIdx.x & 63;
  if (t >= T_TOK) return;
  const float* hr = h + (size_t)t * DIM;
  float hreg[32];
#pragma unroll
  for (int j = 0; j < 32; ++j) hreg[j] = hr[lane + 64 * j];
  float p[16];
#pragma unroll
  for (int e = 0; e < 16; ++e) {
    const float* gr = gw + e * DIM;
    float s = 0.f;
#pragma unroll
    for (int j = 0; j < 32; ++j) s += hreg[j] * gr[lane + 64 * j];
#pragma unroll
    for (int off = 32; off; off >>= 1) s += __shfl_xor(s, off);
    p[e] = s;
  }
  float mx = p[0];
#pragma unroll
  for (int e = 1; e < 16; ++e) mx = fmaxf(mx, p[e]);
  float sum = 0.f;
#pragma unroll
  for (int e = 0; e < 16; ++e) { p[e] = expf(p[e] - mx); sum += p[e]; }
  float inv = 1.f / sum;
#pragma unroll
  for (int e = 0; e < 16; ++e) p[e] *= inv;
  if (lane < 16) {
    float mine = p[lane];
    int rank = 0;
#pragma unroll
    for (int j = 0; j < 16; ++j)
      rank += (p[j] > mine) || (p[j] == mine && j < lane);  // jax top_k tie-break
    if (rank < TOPK) {
      int pos = atomicAdd(&cnt[lane], 1);
      tok[lane * T_TOK + pos] = t;
      wt [lane * T_TOK + pos] = mine;
    }
  }
}

// ------------- fp32 -> scaled fp16 hi/lo split (x*64 = hi + lo) -------------
__global__ __launch_bounds__(256) void split_kernel(
    const float* __restrict__ src, f16* __restrict__ hi, f16* __restrict__ lo, int n4)
{
  int i0 = blockIdx.x * 256 + threadIdx.x;
  int stride = gridDim.x * 256;
  for (int i = i0; i < n4; i += stride) {
    fv4 v = ((const fv4*)src)[i];
    f16x4 h4, l4;
#pragma unroll
    for (int j = 0; j < 4; ++j) {
      float x = v[j] * 64.f;       // pre-scale keeps lo parts out of fp16 denormal range
      f16 hh = (f16)x;
      h4[j] = hh;
      l4[j] = (f16)(x - (float)hh);
    }
    ((f16x4*)hi)[i] = h4;
    ((f16x4*)lo)[i] = l4;
  }
}

// ---------------- gathered grouped GEMM, 256x256 tile, pipelined ------------
// 3-term emulated-fp32 product as ONE GEMM with K tripled:
//   ktg in [0,32):  A1*W1   [32,64): A1*W2   [64,96): A2*W1
// 8 waves (2M x 4N), wave tile 128x64, BK=64, dbuf LDS 128 KB,
// raw s_barrier + counted vmcnt (T3+T4), setprio around MFMA (T5),
// global_load_lds w=16 with pre-swizzled global src + swizzled ds_read (T2).
__global__ __launch_bounds__(512, 2) void moe_gemm(
    const f16* __restrict__ A1, const f16* __restrict__ A2,
    const f16* __restrict__ W1, const f16* __restrict__ W2,
    const int* __restrict__ tok, const float* __restrict__ wt,
    const int* __restrict__ cnt, float* __restrict__ out)
{
  const int e  = blockIdx.z;
  const int ce = cnt[e];
  const int m0 = blockIdx.y * BM;
  if (m0 >= ce) return;
  const int n0 = blockIdx.x * BN;

  __shared__ f16 lsA[2][BM * BK];
  __shared__ f16 lsB[2][BN * BK];

  const int tid = threadIdx.x;

  // --- staging geometry: op j covers rows [j*64, j*64+64), thread -> (row, chunk)
  // LDS linear dest = j*4096 + tid*8 elems (wave-uniform base + lane*16B).
  // global source chunk is pre-swizzled: c ^ (row&7).
  const int srow = tid >> 3;          // 0..63
  const int scol = tid & 7;
  size_t aoff[4], boff[4];
#pragma unroll
  for (int j = 0; j < 4; ++j) {
    int row  = j * 64 + srow;
    int swz  = scol ^ (row & 7);
    int lpos = min(m0 + row, ce - 1);
    int gtok = tok[e * T_TOK + lpos];
    aoff[j] = (size_t)gtok * DIM + swz * 8;
    boff[j] = ((size_t)e * DIM + n0 + row) * DIM + swz * 8;
  }

  auto stage = [&](int ktg, int b) {
    const f16* As = (ktg < 64) ? A1 : A2;
    const f16* Bs = (ktg >= 32 && ktg < 64) ? W2 : W1;
    const int  kl = (ktg & 31) * BK;
#pragma unroll
    for (int j = 0; j < 4; ++j) {
      __builtin_amdgcn_global_load_lds(
          (const __attribute__((address_space(1))) void*)(As + aoff[j] + kl),
          (__attribute__((address_space(3))) void*)(&lsA[b][j * 4096 + tid * 8]), 16, 0, 0);
      __builtin_amdgcn_global_load_lds(
          (const __attribute__((address_space(1))) void*)(Bs + boff[j] + kl),
          (__attribute__((address_space(3))) void*)(&lsB[b][j * 4096 + tid * 8]), 16, 0, 0);
    }
  };

  const int lane = tid & 63;
  const int wid  = tid >> 6;
  const int wm   = wid & 1;           // M half (128 rows)
  const int wn   = wid >> 1;          // N quarter (64 cols)
  const int lr   = lane & 15;
  const int lk   = lane >> 4;         // 0..3

  f32x4 acc[8][4];
#pragma unroll
  for (int i = 0; i < 8; ++i)
#pragma unroll
    for (int j = 0; j < 4; ++j)
      acc[i][j] = (f32x4){0.f, 0.f, 0.f, 0.f};

  stage(0, 0);
  stage(1, 1);
  asm volatile("s_waitcnt vmcnt(8)" ::: "memory");
  __builtin_amdgcn_s_barrier();
  __builtin_amdgcn_sched_barrier(0);

  int cur = 0;
  for (int kt = 0; kt < NT; ++kt) {
    const f16* bufA = lsA[cur];
    const f16* bufB = lsB[cur];
    f16x8 aF[8], bF[4];

    // ---- K-half 0: read frags, MFMA
#pragma unroll
    for (int mi = 0; mi < 8; ++mi) {
      int r = wm * 128 + mi * 16 + lr;
      aF[mi] = *(const f16x8*)&bufA[r * BK + ((lk ^ (r & 7)) * 8)];
    }
#pragma unroll
    for (int ni = 0; ni < 4; ++ni) {
      int r = wn * 64 + ni * 16 + lr;
      bF[ni] = *(const f16x8*)&bufB[r * BK + ((lk ^ (r & 7)) * 8)];
    }
    __builtin_amdgcn_s_setprio(1);
#pragma unroll
    for (int mi = 0; mi < 8; ++mi)
#pragma unroll
      for (int ni = 0; ni < 4; ++ni)
        acc[mi][ni] = __builtin_amdgcn_mfma_f32_16x16x32_f16(aF[mi], bF[ni], acc[mi][ni], 0, 0, 0);
    __builtin_amdgcn_s_setprio(0);

    // ---- K-half 1: read frags, then free the buffer, restage, MFMA
#pragma unroll
    for (int mi = 0; mi < 8; ++mi) {
      int r = wm * 128 + mi * 16 + lr;
      int c = 4 + lk;
      aF[mi] = *(const f16x8*)&bufA[r * BK + ((c ^ (r & 7)) * 8)];
    }
#pragma unroll
    for (int ni = 0; ni < 4; ++ni) {
      int r = wn * 64 + ni * 16 + lr;
      int c = 4 + lk;
      bF[ni] = *(const f16x8*)&bufB[r * BK + ((c ^ (r & 7)) * 8)];
    }
    asm volatile("s_waitcnt lgkmcnt(0)" ::: "memory");   // frags in regs
    __builtin_amdgcn_sched_barrier(0);
    __builtin_amdgcn_s_barrier();                        // all waves done reading buf[cur]
    __builtin_amdgcn_sched_barrier(0);
    if (kt + 2 < NT) stage(kt + 2, cur);                 // overwrite freed buffer

    __builtin_amdgcn_s_setprio(1);
#pragma unroll
    for (int mi = 0; mi < 8; ++mi)
#pragma unroll
      for (int ni = 0; ni < 4; ++ni)
        acc[mi][ni] = __builtin_amdgcn_mfma_f32_16x16x32_f16(aF[mi], bF[ni], acc[mi][ni], 0, 0, 0);
    __builtin_amdgcn_s_setprio(0);

    if (kt + 1 < NT) {
      if (kt + 2 < NT) asm volatile("s_waitcnt vmcnt(8)" ::: "memory");  // kt+1 landed, kt+2 in flight
      else             asm volatile("s_waitcnt vmcnt(0)" ::: "memory");
      __builtin_amdgcn_sched_barrier(0);
      __builtin_amdgcn_s_barrier();
      __builtin_amdgcn_sched_barrier(0);
      cur ^= 1;
    }
  }

  // epilogue: out[tok, n] += w * acc / 4096  (descale 64*64)
  const int ebase = e * T_TOK;
#pragma unroll
  for (int mi = 0; mi < 8; ++mi) {
#pragma unroll
    for (int q = 0; q < 4; ++q) {
      int pos = m0 + wm * 128 + mi * 16 + lk * 4 + q;
      if (pos < ce) {
        int tt = tok[ebase + pos];
        float sc = wt[ebase + pos] * (1.0f / 4096.0f);
        float* orow = out + (size_t)tt * DIM + n0 + wn * 64;
#pragma unroll
        for (int ni = 0; ni < 4; ++ni)
          atomicAdd(&orow[ni * 16 + lr], sc * acc[mi][ni][q]);
      }
    }
  }
}

// ------------------------------- launcher -----------------------------------
extern "C" void kernel_launch(void* const* d_in, const int* in_sizes, int n_in,
                              void* d_out, int out_size, void* d_ws, size_t ws_size,
                              hipStream_t stream) {
  const float* x  = (const float*)d_in[0];
  const float* gw = (const float*)d_in[1];
  const float* ew = (const float*)d_in[2];
  float* out = (float*)d_out;

  char* ws = (char*)d_ws;
  float* hA  = (float*)ws;                        // 64 MB fp32 h ping buffer
  f16*   A1  = (f16*)(ws + 67108864ull);          // 32 MB
  f16*   A2  = (f16*)(ws + 100663296ull);         // 32 MB
  f16*   W1  = (f16*)(ws + 134217728ull);         // 128 MB (current layer)
  f16*   W2  = (f16*)(ws + 268435456ull);         // 128 MB
  int*   tok = (int*)(ws + 402653184ull);         // 512 KB
  float* wt  = (float*)(ws + 403177472ull);       // 512 KB
  int*   cnt = (int*)(ws + 403701760ull);         // 64 B

  const float* hin = x;
  float* houts[4] = {hA, out, hA, out};           // ping-pong; final layer -> d_out
  for (int l = 0; l < NLAY; ++l) {
    float* hout = houts[l];
    hipMemsetAsync(cnt, 0, 64, stream);
    route_kernel<<<T_TOK / 4, 256, 0, stream>>>(hin, gw + (size_t)l * NEXP * DIM, cnt, tok, wt);
    split_kernel<<<4096, 256, 0, stream>>>(hin, A1, A2, T_TOK * DIM / 4);
    split_kernel<<<8192, 256, 0, stream>>>(ew + (size_t)l * NEXP * DIM * DIM, W1, W2, NEXP * DIM * DIM / 4);
    hipMemsetAsync(hout, 0, (size_t)T_TOK * DIM * 4, stream);
    dim3 g(DIM / BN, T_TOK / BM, NEXP);
    moe_gemm<<<g, 512, 0, stream>>>(A1, A2, W1, W2, tok, wt, cnt, hout);
    hin = hout;
  }
}